// Round 7
// baseline (274.001 us; speedup 1.0000x reference)
//
#include <hip/hip_runtime.h>

// Shapes: x [32][256][56][56] f32; fc1_w [65][256]; fc2_w [4][65]; fc2_b [4];
//         weight [4][256][256][3][3] f32; bias [4][256]; out [32][256][56][56] f32
//
// ws layout (89,195,008 B):
//  [0)        pooled [32][256] f32 (REUSED as 1KB zerobuf for conv)   32768 B
//  [32768)    att    [32][4]  f32                                       512 B
//  [33280)    aggb   [32][256] f32                                    32768 B
//  [66048)    aggw   [32][2][16][9][128][16] bf16 (plain)        37,748,736 B
//  [37814784) xb     [32][3136][256] bf16 (NHWC, plain)          51,380,224 B

typedef short bf16x8 __attribute__((ext_vector_type(8)));
typedef float f32x16 __attribute__((ext_vector_type(16)));

__device__ __forceinline__ unsigned short f2bf(float f) {
  unsigned int u = __float_as_uint(f);
  return (unsigned short)((u + 0x7FFFu + ((u >> 16) & 1u)) >> 16);  // RNE
}
__device__ __forceinline__ float bf2f(unsigned short h) {
  return __uint_as_float(((unsigned int)h) << 16);
}

// forward LDS swizzle: S = L ^ (((L>>5)&7)<<4); inverse below (bit recurrence)
__device__ __forceinline__ int invswz(int S) {
  int b7 = (S >> 7) & 1;
  int b6 = ((S >> 6) & 1) ^ b7;
  int b5 = ((S >> 5) & 1) ^ b6;
  int b4 = ((S >> 4) & 1) ^ b5;
  return (S & ~0x70) | (b4 << 4) | (b5 << 5) | (b6 << 6);
}

typedef const __attribute__((address_space(1))) unsigned int* gas_t;
typedef __attribute__((address_space(3))) unsigned int* las_t;
__device__ __forceinline__ void dma16(const void* g, unsigned lds_addr) {
  __builtin_amdgcn_global_load_lds((gas_t)g, (las_t)(size_t)lds_addr, 16, 0, 0);
}

// ---------------- K1: x NCHW f32 -> NHWC bf16 (float4 loads), fused avg-pool --------
__global__ void xcast_k(const float* __restrict__ x, unsigned short* __restrict__ xb,
                        float* __restrict__ pooled) {
  __shared__ unsigned short tile[64 * 260];  // 64 hw x 256 c (+4 pad)
  int b = blockIdx.y;
  int hw0 = blockIdx.x * 64;   // 49*64 = 3136
  int t = threadIdx.x;
  int p = t & 15, g = t >> 4;
#pragma unroll
  for (int i = 0; i < 16; ++i) {
    int c = g + 16 * i;
    float4 v = *(const float4*)(x + ((size_t)(b * 256 + c)) * 3136 + hw0 + p * 4);
    tile[(p * 4 + 0) * 260 + c] = f2bf(v.x);
    tile[(p * 4 + 1) * 260 + c] = f2bf(v.y);
    tile[(p * 4 + 2) * 260 + c] = f2bf(v.z);
    tile[(p * 4 + 3) * 260 + c] = f2bf(v.w);
  }
  __syncthreads();
  int lane = t & 63, wq = t >> 6;
  int c4 = lane * 4;
#pragma unroll
  for (int it = 0; it < 16; ++it) {
    int hl = it * 4 + wq;
    ushort4 v = *(const ushort4*)&tile[hl * 260 + c4];
    *(ushort4*)&xb[((size_t)(b * 3136 + hw0 + hl)) * 256 + c4] = v;
  }
  float s = 0.f;
#pragma unroll 16
  for (int hl = 0; hl < 64; ++hl) s += bf2f(tile[hl * 260 + t]);
  atomicAdd(&pooled[b * 256 + t], s * (1.0f / 3136.0f));
}

// ---------------- K2: attention (fc1->relu->fc2->softmax/T) + agg_b ----------------
__global__ void att_k(const float* __restrict__ pooled, const float* __restrict__ fc1,
                      const float* __restrict__ fc2w, const float* __restrict__ fc2b,
                      const float* __restrict__ bias, float* __restrict__ att,
                      float* __restrict__ aggb) {
  int b = blockIdx.x, t = threadIdx.x;   // 64 threads
  __shared__ float p[256];
  __shared__ float h[65];
  __shared__ float a4[4];
  for (int i = t; i < 256; i += 64) p[i] = pooled[b * 256 + i];
  __syncthreads();
  for (int j = t; j < 65; j += 64) {
    float s = 0.f;
    for (int c = 0; c < 256; ++c) s += p[c] * fc1[j * 256 + c];
    h[j] = fmaxf(s, 0.f);
  }
  __syncthreads();
  if (t == 0) {
    float lg[4];
    for (int k = 0; k < 4; ++k) {
      float s = fc2b[k];
      for (int j = 0; j < 65; ++j) s += h[j] * fc2w[k * 65 + j];
      lg[k] = s * (1.0f / 34.0f);
    }
    float m = fmaxf(fmaxf(lg[0], lg[1]), fmaxf(lg[2], lg[3]));
    float e0 = expf(lg[0] - m), e1 = expf(lg[1] - m), e2 = expf(lg[2] - m), e3 = expf(lg[3] - m);
    float inv = 1.0f / (e0 + e1 + e2 + e3);
    a4[0] = e0 * inv; a4[1] = e1 * inv; a4[2] = e2 * inv; a4[3] = e3 * inv;
    for (int k = 0; k < 4; ++k) att[b * 4 + k] = a4[k];
  }
  __syncthreads();
  for (int o = t; o < 256; o += 64) {
    float s = 0.f;
    for (int k = 0; k < 4; ++k) s += a4[k] * bias[k * 256 + o];
    aggb[b * 256 + o] = s;
  }
}

// ---------------- K3: agg_w -> [b][ot2][ic16][r9][ol128][il16] bf16 (plain) ----------
__global__ void aggw_k(const float* __restrict__ weight, const float* __restrict__ att,
                       unsigned short* __restrict__ aggw) {
  __shared__ float wl[4 * 2304];
  int o = blockIdx.x, t = threadIdx.x;   // t = input channel i
  for (int k = 0; k < 4; ++k)
    for (int idx = t; idx < 2304; idx += 256)
      wl[k * 2304 + idx] = weight[((size_t)(k * 256 + o)) * 2304 + idx];
  __syncthreads();
  int ot = o >> 7, ol = o & 127, ic = t >> 4, il = t & 15;
  int b0 = blockIdx.y * 8;
  for (int b = b0; b < b0 + 8; ++b) {
    float a0 = att[b * 4 + 0], a1 = att[b * 4 + 1], a2 = att[b * 4 + 2], a3 = att[b * 4 + 3];
    size_t base = ((size_t)((b * 2 + ot) * 16 + ic)) * (9 * 2048) + ol * 16 + il;
#pragma unroll
    for (int r = 0; r < 9; ++r) {
      float s = a0 * wl[t * 9 + r] + a1 * wl[2304 + t * 9 + r] +
                a2 * wl[4608 + t * 9 + r] + a3 * wl[6912 + t * 9 + r];
      aggw[base + r * 2048] = f2bf(s);
    }
  }
}

// ---------------- K4: conv, DMA staging, BOTH operands double-buffered --------------
// 256 thr (4 waves = 2wo x 2wn). Block tile 128o x 256n; wave 64o x 128n (2m x 4n).
// K: 16 chunks of 16 ch. One barrier per chunk: all DMAs for chunk ic+1 issue at the
// TOP of compute(ic); the barrier's vmcnt(0) drain then waits on ~2300-cycle-old DMAs.
// LDS (dynamic, 106,496B -> 1 block/CU): X dbuf 2x16KB @0, A dbuf 2x36864B @32768.
#define XBUF 16384
#define AOFF 32768
#define ABUF 36864

__global__ __launch_bounds__(256, 1) void conv_k(const unsigned short* __restrict__ xb,
                                                 const unsigned short* __restrict__ aggw,
                                                 const float* __restrict__ aggb,
                                                 const float* __restrict__ zerobuf,
                                                 float* __restrict__ out) {
  extern __shared__ unsigned char lds[];
  const unsigned ldsbase = (unsigned)(size_t)&lds[0];
  const int t = threadIdx.x;
  const int wid = t >> 6, lane = t & 63, l31 = lane & 31, q = lane >> 5;
  const int wo = wid >> 1, wn = wid & 1;

  // XCD-chunked bijective swizzle: 832 blocks = 8 XCDs x 104
  int id = blockIdx.x;
  int wgid = (id & 7) * 104 + (id >> 3);
  int bn = wgid % 13;
  int rest = wgid / 13;          // = b*2 + bo
  int b = rest >> 1, bo = rest & 1;

  const int o0 = bo * 128;
  const int n0 = bn * 256;
  const int h0 = n0 / 56;

  // B (X-tile) fragment geometry (read side, forward swizzle)
  int bbase[4], nn[4], swz[4][3];
#pragma unroll
  for (int nf = 0; nf < 4; ++nf) {
    int n = n0 + wn * 128 + nf * 32 + l31;
    int h = n / 56, w = n - h * 56;
    nn[nf] = n;
    bbase[nf] = ((h - h0) * 64 + w) * 32 + q * 16;
#pragma unroll
    for (int dw = 0; dw < 3; ++dw) swz[nf][dw] = ((w + dw) & 7) << 4;
  }
  // A fragment LDS offsets (lane-constant forward swizzle), relative to A buffer base
  int abase[2];
#pragma unroll
  for (int mf = 0; mf < 2; ++mf) {
    int ol = wo * 64 + mf * 32 + l31;
    abase[mf] = (ol * 32 + q * 16) ^ ((ol & 7) << 4);
  }

  const char* xb_b = (const char*)xb + (size_t)b * 3136 * 512;
  const char* ag_c = (const char*)aggw + (size_t)rest * 589824;

  // per-lane DMA source addresses (inverse swizzle -> linear LDS dest)
  const char* xg[4];
#pragma unroll
  for (int j = 0; j < 4; ++j) {
    int S = (j * 256 + t) * 16;
    int L = invswz(S);
    int pos = L >> 5, sub = (L >> 4) & 1;
    int row = pos >> 6, col = pos & 63;
    int hg = h0 - 1 + row, wg = col - 1;
    bool valid = (col >= 1 && col <= 56 && hg >= 0 && hg < 56);
    xg[j] = valid ? (xb_b + (size_t)(hg * 56 + wg) * 512 + sub * 16) : (const char*)zerobuf;
  }
  const char* aL = ag_c + invswz(t * 16);   // invswz touches bits 4-6 only; +j*4096/+ic*36864 safe

  f32x16 acc[2][4];
#pragma unroll
  for (int i = 0; i < 2; ++i)
#pragma unroll
    for (int j = 0; j < 4; ++j)
#pragma unroll
      for (int e = 0; e < 16; ++e) acc[i][j][e] = 0.f;

  // prologue: DMA chunk 0 into buffers 0
#pragma unroll
  for (int j = 0; j < 4; ++j) dma16(xg[j], ldsbase + j * 4096 + wid * 1024);
#pragma unroll
  for (int j = 0; j < 9; ++j) dma16(aL + j * 4096, ldsbase + AOFF + j * 4096 + wid * 1024);
  __syncthreads();

  int cur = 0;
  for (int ic = 0; ic < 16; ++ic) {
    // issue ALL of chunk ic+1's DMAs before compute(ic); latency hides under 9r of MFMA
    if (ic + 1 < 16) {
      const int nxt = cur ^ 1;
#pragma unroll
      for (int j = 0; j < 4; ++j)
        dma16(xg[j] + (ic + 1) * 32, ldsbase + nxt * XBUF + j * 4096 + wid * 1024);
#pragma unroll
      for (int j = 0; j < 9; ++j)
        dma16(aL + (size_t)(ic + 1) * ABUF + j * 4096,
              ldsbase + AOFF + nxt * ABUF + j * 4096 + wid * 1024);
      __builtin_amdgcn_sched_barrier(0);   // pin DMA issue ahead of the read/MFMA stream
    }
    const unsigned char* xlds = lds + cur * XBUF;
    const unsigned char* alds = lds + AOFF + cur * ABUF;
#pragma unroll
    for (int r = 0; r < 9; ++r) {
      const int dh = r / 3, dw = r % 3;
      bf16x8 a0 = *(const bf16x8*)(alds + abase[0] + r * 4096);
      bf16x8 a1 = *(const bf16x8*)(alds + abase[1] + r * 4096);
      bf16x8 b0 = *(const bf16x8*)(xlds + ((bbase[0] + dh * 2048 + dw * 32) ^ swz[0][dw]));
      bf16x8 b1 = *(const bf16x8*)(xlds + ((bbase[1] + dh * 2048 + dw * 32) ^ swz[1][dw]));
      bf16x8 b2 = *(const bf16x8*)(xlds + ((bbase[2] + dh * 2048 + dw * 32) ^ swz[2][dw]));
      bf16x8 b3 = *(const bf16x8*)(xlds + ((bbase[3] + dh * 2048 + dw * 32) ^ swz[3][dw]));
      __builtin_amdgcn_s_setprio(1);
      acc[0][0] = __builtin_amdgcn_mfma_f32_32x32x16_bf16(a0, b0, acc[0][0], 0, 0, 0);
      acc[0][1] = __builtin_amdgcn_mfma_f32_32x32x16_bf16(a0, b1, acc[0][1], 0, 0, 0);
      acc[0][2] = __builtin_amdgcn_mfma_f32_32x32x16_bf16(a0, b2, acc[0][2], 0, 0, 0);
      acc[0][3] = __builtin_amdgcn_mfma_f32_32x32x16_bf16(a0, b3, acc[0][3], 0, 0, 0);
      acc[1][0] = __builtin_amdgcn_mfma_f32_32x32x16_bf16(a1, b0, acc[1][0], 0, 0, 0);
      acc[1][1] = __builtin_amdgcn_mfma_f32_32x32x16_bf16(a1, b1, acc[1][1], 0, 0, 0);
      acc[1][2] = __builtin_amdgcn_mfma_f32_32x32x16_bf16(a1, b2, acc[1][2], 0, 0, 0);
      acc[1][3] = __builtin_amdgcn_mfma_f32_32x32x16_bf16(a1, b3, acc[1][3], 0, 0, 0);
      __builtin_amdgcn_s_setprio(0);
    }
    __syncthreads();   // single barrier/chunk; vmcnt drain waits on ~2300-cyc-old DMAs
    cur ^= 1;
  }

  // ---- epilogue: D layout col=lane&31 (n), row=(reg&3)+8*(reg>>2)+4*q (o)
#pragma unroll
  for (int mf = 0; mf < 2; ++mf) {
#pragma unroll
    for (int reg = 0; reg < 16; ++reg) {
      int o = o0 + wo * 64 + mf * 32 + (reg & 3) + 8 * (reg >> 2) + 4 * q;
      float ab = aggb[b * 256 + o];
      float* op = out + ((size_t)(b * 256 + o)) * 3136;
#pragma unroll
      for (int nf = 0; nf < 4; ++nf) {
        if (nn[nf] < 3136) op[nn[nf]] = acc[mf][nf][reg] + ab;
      }
    }
  }
}

extern "C" void kernel_launch(void* const* d_in, const int* in_sizes, int n_in,
                              void* d_out, int out_size, void* d_ws, size_t ws_size,
                              hipStream_t stream) {
  const float* x      = (const float*)d_in[0];
  const float* fc1    = (const float*)d_in[1];
  const float* fc2w   = (const float*)d_in[2];
  const float* fc2b   = (const float*)d_in[3];
  const float* weight = (const float*)d_in[4];
  const float* bias   = (const float*)d_in[5];
  float* out = (float*)d_out;

  char* ws = (char*)d_ws;
  float* pooled         = (float*)(ws);            // reused as zerobuf after att_k
  float* att            = (float*)(ws + 32768);
  float* aggb           = (float*)(ws + 33280);
  unsigned short* aggw  = (unsigned short*)(ws + 66048);
  unsigned short* xb    = (unsigned short*)(ws + 66048 + 37748736);

  hipFuncSetAttribute(reinterpret_cast<const void*>(conv_k),
                      hipFuncAttributeMaxDynamicSharedMemorySize, 2 * XBUF + 2 * ABUF);

  hipMemsetAsync(pooled, 0, 32768, stream);          // pooled accumulated via atomics
  xcast_k<<<dim3(49, 32), 256, 0, stream>>>(x, xb, pooled);
  att_k<<<32, 64, 0, stream>>>(pooled, fc1, fc2w, fc2b, bias, att, aggb);
  hipMemsetAsync(pooled, 0, 1024, stream);           // pooled now dead -> 1KB zerobuf for halo
  aggw_k<<<dim3(256, 4), 256, 0, stream>>>(weight, att, aggw);
  conv_k<<<832, 256, 2 * XBUF + 2 * ABUF, stream>>>(xb, aggw, aggb, (const float*)pooled, out);
}

// Round 8
// 257.104 us; speedup vs baseline: 1.0657x; 1.0657x over previous
//
#include <hip/hip_runtime.h>

// Shapes: x [32][256][56][56] f32; fc1_w [65][256]; fc2_w [4][65]; fc2_b [4];
//         weight [4][256][256][3][3] f32; bias [4][256]; out [32][256][56][56] f32
//
// ws layout (89,195,008 B):
//  [0)        pooled [32][256] f32 (REUSED as 1KB zerobuf for conv)   32768 B
//  [32768)    att    [32][4]  f32                                       512 B
//  [33280)    aggb   [32][256] f32                                    32768 B
//  [66048)    aggw   [32][2][16][9][128][16] bf16 (plain)        37,748,736 B
//  [37814784) xb     [32][3136][256] bf16 (NHWC, plain)          51,380,224 B

typedef short bf16x8 __attribute__((ext_vector_type(8)));
typedef float f32x16 __attribute__((ext_vector_type(16)));

__device__ __forceinline__ unsigned short f2bf(float f) {
  unsigned int u = __float_as_uint(f);
  return (unsigned short)((u + 0x7FFFu + ((u >> 16) & 1u)) >> 16);  // RNE
}
__device__ __forceinline__ float bf2f(unsigned short h) {
  return __uint_as_float(((unsigned int)h) << 16);
}

// forward LDS swizzle: S = L ^ (((L>>5)&7)<<4); inverse below (bit recurrence)
__device__ __forceinline__ int invswz(int S) {
  int b7 = (S >> 7) & 1;
  int b6 = ((S >> 6) & 1) ^ b7;
  int b5 = ((S >> 5) & 1) ^ b6;
  int b4 = ((S >> 4) & 1) ^ b5;
  return (S & ~0x70) | (b4 << 4) | (b5 << 5) | (b6 << 6);
}

typedef const __attribute__((address_space(1))) unsigned int* gas_t;
typedef __attribute__((address_space(3))) unsigned int* las_t;
__device__ __forceinline__ void dma16(const void* g, unsigned lds_addr) {
  __builtin_amdgcn_global_load_lds((gas_t)g, (las_t)(size_t)lds_addr, 16, 0, 0);
}

// ---------------- K1: x NCHW f32 -> NHWC bf16 (float4 loads), fused avg-pool --------
__global__ void xcast_k(const float* __restrict__ x, unsigned short* __restrict__ xb,
                        float* __restrict__ pooled) {
  __shared__ unsigned short tile[64 * 260];  // 64 hw x 256 c (+4 pad)
  int b = blockIdx.y;
  int hw0 = blockIdx.x * 64;   // 49*64 = 3136
  int t = threadIdx.x;
  int p = t & 15, g = t >> 4;
#pragma unroll
  for (int i = 0; i < 16; ++i) {
    int c = g + 16 * i;
    float4 v = *(const float4*)(x + ((size_t)(b * 256 + c)) * 3136 + hw0 + p * 4);
    tile[(p * 4 + 0) * 260 + c] = f2bf(v.x);
    tile[(p * 4 + 1) * 260 + c] = f2bf(v.y);
    tile[(p * 4 + 2) * 260 + c] = f2bf(v.z);
    tile[(p * 4 + 3) * 260 + c] = f2bf(v.w);
  }
  __syncthreads();
  int lane = t & 63, wq = t >> 6;
  int c4 = lane * 4;
#pragma unroll
  for (int it = 0; it < 16; ++it) {
    int hl = it * 4 + wq;
    ushort4 v = *(const ushort4*)&tile[hl * 260 + c4];
    *(ushort4*)&xb[((size_t)(b * 3136 + hw0 + hl)) * 256 + c4] = v;
  }
  float s = 0.f;
#pragma unroll 16
  for (int hl = 0; hl < 64; ++hl) s += bf2f(tile[hl * 260 + t]);
  atomicAdd(&pooled[b * 256 + t], s * (1.0f / 3136.0f));
}

// ---------------- K2: attention (fc1->relu->fc2->softmax/T) + agg_b ----------------
__global__ void att_k(const float* __restrict__ pooled, const float* __restrict__ fc1,
                      const float* __restrict__ fc2w, const float* __restrict__ fc2b,
                      const float* __restrict__ bias, float* __restrict__ att,
                      float* __restrict__ aggb) {
  int b = blockIdx.x, t = threadIdx.x;   // 64 threads
  __shared__ float p[256];
  __shared__ float h[65];
  __shared__ float a4[4];
  for (int i = t; i < 256; i += 64) p[i] = pooled[b * 256 + i];
  __syncthreads();
  for (int j = t; j < 65; j += 64) {
    float s = 0.f;
    for (int c = 0; c < 256; ++c) s += p[c] * fc1[j * 256 + c];
    h[j] = fmaxf(s, 0.f);
  }
  __syncthreads();
  if (t == 0) {
    float lg[4];
    for (int k = 0; k < 4; ++k) {
      float s = fc2b[k];
      for (int j = 0; j < 65; ++j) s += h[j] * fc2w[k * 65 + j];
      lg[k] = s * (1.0f / 34.0f);
    }
    float m = fmaxf(fmaxf(lg[0], lg[1]), fmaxf(lg[2], lg[3]));
    float e0 = expf(lg[0] - m), e1 = expf(lg[1] - m), e2 = expf(lg[2] - m), e3 = expf(lg[3] - m);
    float inv = 1.0f / (e0 + e1 + e2 + e3);
    a4[0] = e0 * inv; a4[1] = e1 * inv; a4[2] = e2 * inv; a4[3] = e3 * inv;
    for (int k = 0; k < 4; ++k) att[b * 4 + k] = a4[k];
  }
  __syncthreads();
  for (int o = t; o < 256; o += 64) {
    float s = 0.f;
    for (int k = 0; k < 4; ++k) s += a4[k] * bias[k * 256 + o];
    aggb[b * 256 + o] = s;
  }
}

// ---------------- K3: agg_w -> [b][ot2][ic16][r9][ol128][il16] bf16 (plain) ----------
__global__ void aggw_k(const float* __restrict__ weight, const float* __restrict__ att,
                       unsigned short* __restrict__ aggw) {
  __shared__ float wl[4 * 2304];
  int o = blockIdx.x, t = threadIdx.x;   // t = input channel i
  for (int k = 0; k < 4; ++k)
    for (int idx = t; idx < 2304; idx += 256)
      wl[k * 2304 + idx] = weight[((size_t)(k * 256 + o)) * 2304 + idx];
  __syncthreads();
  int ot = o >> 7, ol = o & 127, ic = t >> 4, il = t & 15;
  int b0 = blockIdx.y * 8;
  for (int b = b0; b < b0 + 8; ++b) {
    float a0 = att[b * 4 + 0], a1 = att[b * 4 + 1], a2 = att[b * 4 + 2], a3 = att[b * 4 + 3];
    size_t base = ((size_t)((b * 2 + ot) * 16 + ic)) * (9 * 2048) + ol * 16 + il;
#pragma unroll
    for (int r = 0; r < 9; ++r) {
      float s = a0 * wl[t * 9 + r] + a1 * wl[2304 + t * 9 + r] +
                a2 * wl[4608 + t * 9 + r] + a3 * wl[6912 + t * 9 + r];
      aggw[base + r * 2048] = f2bf(s);
    }
  }
}

// ---------------- K4: conv; A global->regs (whole chunk), X LDS dbuf via DMA --------
// 256 thr (4 waves = 2wo x 2wn). Block tile 128o x 256n; wave 64o x 128n (2m x 4n).
// K: 16 chunks of 16 ch. LDS: X only, 2 x 16KB (static 32KB -> 2 blocks/CU).
// Per chunk per wave: 18 coalesced global A-loads (one vmcnt wait), 36 LDS B-reads.
#define XBUF 16384

__global__ __launch_bounds__(256, 2) void conv_k(const unsigned short* __restrict__ xb,
                                                 const unsigned short* __restrict__ aggw,
                                                 const float* __restrict__ aggb,
                                                 const float* __restrict__ zerobuf,
                                                 float* __restrict__ out) {
  __shared__ __align__(16) unsigned char lds[2 * XBUF];
  const unsigned ldsbase = (unsigned)(size_t)&lds[0];
  const int t = threadIdx.x;
  const int wid = t >> 6, lane = t & 63, l31 = lane & 31, q = lane >> 5;
  const int wo = wid >> 1, wn = wid & 1;

  // XCD-chunked bijective swizzle: 832 blocks = 8 XCDs x 104; bn fastest within XCD
  int id = blockIdx.x;
  int wgid = (id & 7) * 104 + (id >> 3);
  int bn = wgid % 13;
  int rest = wgid / 13;          // = b*2 + bo
  int b = rest >> 1, bo = rest & 1;

  const int o0 = bo * 128;
  const int n0 = bn * 256;
  const int h0 = n0 / 56;

  // B (X-tile) fragment geometry (read side, forward swizzle)
  int bbase[4], nn[4], swz[4][3];
#pragma unroll
  for (int nf = 0; nf < 4; ++nf) {
    int n = n0 + wn * 128 + nf * 32 + l31;
    int h = n / 56, w = n - h * 56;
    nn[nf] = n;
    bbase[nf] = ((h - h0) * 64 + w) * 32 + q * 16;
#pragma unroll
    for (int dw = 0; dw < 3; ++dw) swz[nf][dw] = ((w + dw) & 7) << 4;
  }
  // A fragment global lane offsets (aggw layout == frag layout; no swizzle needed)
  int aoff[2];
#pragma unroll
  for (int mf = 0; mf < 2; ++mf) aoff[mf] = (wo * 64 + mf * 32 + l31) * 32 + q * 16;

  const char* xb_b = (const char*)xb + (size_t)b * 3136 * 512;
  const char* ag_c = (const char*)aggw + (size_t)rest * 589824;   // [16 ic][9 r][128 ol][16 il]*2B

  // X DMA source addresses (inverse swizzle -> linear LDS dest)
  const char* xg[4];
#pragma unroll
  for (int j = 0; j < 4; ++j) {
    int S = (j * 256 + t) * 16;
    int L = invswz(S);
    int pos = L >> 5, sub = (L >> 4) & 1;
    int row = pos >> 6, col = pos & 63;
    int hg = h0 - 1 + row, wg = col - 1;
    bool valid = (col >= 1 && col <= 56 && hg >= 0 && hg < 56);
    xg[j] = valid ? (xb_b + (size_t)(hg * 56 + wg) * 512 + sub * 16) : (const char*)zerobuf;
  }

  f32x16 acc[2][4];
#pragma unroll
  for (int i = 0; i < 2; ++i)
#pragma unroll
    for (int j = 0; j < 4; ++j)
#pragma unroll
      for (int e = 0; e < 16; ++e) acc[i][j][e] = 0.f;

  // prologue: DMA X chunk 0 -> buf 0
#pragma unroll
  for (int j = 0; j < 4; ++j) dma16(xg[j], ldsbase + j * 4096 + wid * 1024);
  __syncthreads();

  int cur = 0;
  for (int ic = 0; ic < 16; ++ic) {
    // A(ic): 18 independent coalesced global loads into registers
    bf16x8 areg[2][9];
    const char* agc = ag_c + (size_t)ic * 36864;
#pragma unroll
    for (int r = 0; r < 9; ++r) {
      areg[0][r] = *(const bf16x8*)(agc + r * 4096 + aoff[0]);
      areg[1][r] = *(const bf16x8*)(agc + r * 4096 + aoff[1]);
    }
    // X-DMA(ic+1) into the other buffer; in flight across this chunk's MFMAs
    if (ic + 1 < 16) {
#pragma unroll
      for (int j = 0; j < 4; ++j)
        dma16(xg[j] + (ic + 1) * 32, ldsbase + (cur ^ 1) * XBUF + j * 4096 + wid * 1024);
    }
    __builtin_amdgcn_sched_barrier(0);   // keep load issue ahead of compute stream
    const unsigned char* xlds = lds + cur * XBUF;
#pragma unroll
    for (int r = 0; r < 9; ++r) {
      const int dh = r / 3, dw = r % 3;
      bf16x8 b0 = *(const bf16x8*)(xlds + ((bbase[0] + dh * 2048 + dw * 32) ^ swz[0][dw]));
      bf16x8 b1 = *(const bf16x8*)(xlds + ((bbase[1] + dh * 2048 + dw * 32) ^ swz[1][dw]));
      bf16x8 b2 = *(const bf16x8*)(xlds + ((bbase[2] + dh * 2048 + dw * 32) ^ swz[2][dw]));
      bf16x8 b3 = *(const bf16x8*)(xlds + ((bbase[3] + dh * 2048 + dw * 32) ^ swz[3][dw]));
      __builtin_amdgcn_s_setprio(1);
      acc[0][0] = __builtin_amdgcn_mfma_f32_32x32x16_bf16(areg[0][r], b0, acc[0][0], 0, 0, 0);
      acc[0][1] = __builtin_amdgcn_mfma_f32_32x32x16_bf16(areg[0][r], b1, acc[0][1], 0, 0, 0);
      acc[0][2] = __builtin_amdgcn_mfma_f32_32x32x16_bf16(areg[0][r], b2, acc[0][2], 0, 0, 0);
      acc[0][3] = __builtin_amdgcn_mfma_f32_32x32x16_bf16(areg[0][r], b3, acc[0][3], 0, 0, 0);
      acc[1][0] = __builtin_amdgcn_mfma_f32_32x32x16_bf16(areg[1][r], b0, acc[1][0], 0, 0, 0);
      acc[1][1] = __builtin_amdgcn_mfma_f32_32x32x16_bf16(areg[1][r], b1, acc[1][1], 0, 0, 0);
      acc[1][2] = __builtin_amdgcn_mfma_f32_32x32x16_bf16(areg[1][r], b2, acc[1][2], 0, 0, 0);
      acc[1][3] = __builtin_amdgcn_mfma_f32_32x32x16_bf16(areg[1][r], b3, acc[1][3], 0, 0, 0);
      __builtin_amdgcn_s_setprio(0);
    }
    __syncthreads();   // X(ic+1) DMA drained (issued ~576 cyc ago); buffers swap
    cur ^= 1;
  }

  // ---- epilogue: D layout col=lane&31 (n), row=(reg&3)+8*(reg>>2)+4*q (o)
#pragma unroll
  for (int mf = 0; mf < 2; ++mf) {
#pragma unroll
    for (int reg = 0; reg < 16; ++reg) {
      int o = o0 + wo * 64 + mf * 32 + (reg & 3) + 8 * (reg >> 2) + 4 * q;
      float ab = aggb[b * 256 + o];
      float* op = out + ((size_t)(b * 256 + o)) * 3136;
#pragma unroll
      for (int nf = 0; nf < 4; ++nf) {
        if (nn[nf] < 3136) op[nn[nf]] = acc[mf][nf][reg] + ab;
      }
    }
  }
}

extern "C" void kernel_launch(void* const* d_in, const int* in_sizes, int n_in,
                              void* d_out, int out_size, void* d_ws, size_t ws_size,
                              hipStream_t stream) {
  const float* x      = (const float*)d_in[0];
  const float* fc1    = (const float*)d_in[1];
  const float* fc2w   = (const float*)d_in[2];
  const float* fc2b   = (const float*)d_in[3];
  const float* weight = (const float*)d_in[4];
  const float* bias   = (const float*)d_in[5];
  float* out = (float*)d_out;

  char* ws = (char*)d_ws;
  float* pooled         = (float*)(ws);            // reused as zerobuf after att_k
  float* att            = (float*)(ws + 32768);
  float* aggb           = (float*)(ws + 33280);
  unsigned short* aggw  = (unsigned short*)(ws + 66048);
  unsigned short* xb    = (unsigned short*)(ws + 66048 + 37748736);

  hipMemsetAsync(pooled, 0, 32768, stream);          // pooled accumulated via atomics
  xcast_k<<<dim3(49, 32), 256, 0, stream>>>(x, xb, pooled);
  att_k<<<32, 64, 0, stream>>>(pooled, fc1, fc2w, fc2b, bias, att, aggb);
  hipMemsetAsync(pooled, 0, 1024, stream);           // pooled now dead -> 1KB zerobuf for halo
  aggw_k<<<dim3(256, 4), 256, 0, stream>>>(weight, att, aggw);
  conv_k<<<832, 256, 0, stream>>>(xb, aggw, aggb, (const float*)pooled, out);
}

// Round 9
// 237.476 us; speedup vs baseline: 1.1538x; 1.0827x over previous
//
#include <hip/hip_runtime.h>

// Shapes: x [32][256][56][56] f32; fc1_w [65][256]; fc2_w [4][65]; fc2_b [4];
//         weight [4][256][256][3][3] f32; bias [4][256]; out [32][256][56][56] f32
//
// ws layout (89,195,008 B):
//  [0)        pooled [32][256] f32 (REUSED as 1KB zerobuf for conv)   32768 B
//  [32768)    att    [32][4]  f32                                       512 B
//  [33280)    aggb   [32][256] f32                                    32768 B
//  [66048)    aggw   [32][2][16][9][128][16] bf16 (plain)        37,748,736 B
//  [37814784) xb     [32][3136][256] bf16 (NHWC, plain)          51,380,224 B

typedef short bf16x8 __attribute__((ext_vector_type(8)));
typedef float f32x16 __attribute__((ext_vector_type(16)));

__device__ __forceinline__ unsigned short f2bf(float f) {
  unsigned int u = __float_as_uint(f);
  return (unsigned short)((u + 0x7FFFu + ((u >> 16) & 1u)) >> 16);  // RNE
}
__device__ __forceinline__ float bf2f(unsigned short h) {
  return __uint_as_float(((unsigned int)h) << 16);
}

// forward LDS swizzle: S = L ^ (((L>>5)&7)<<4); inverse below (bit recurrence)
__device__ __forceinline__ int invswz(int S) {
  int b7 = (S >> 7) & 1;
  int b6 = ((S >> 6) & 1) ^ b7;
  int b5 = ((S >> 5) & 1) ^ b6;
  int b4 = ((S >> 4) & 1) ^ b5;
  return (S & ~0x70) | (b4 << 4) | (b5 << 5) | (b6 << 6);
}

typedef const __attribute__((address_space(1))) unsigned int* gas_t;
typedef __attribute__((address_space(3))) unsigned int* las_t;
__device__ __forceinline__ void dma16(const void* g, unsigned lds_addr) {
  __builtin_amdgcn_global_load_lds((gas_t)g, (las_t)(size_t)lds_addr, 16, 0, 0);
}

// ---------------- K1: x NCHW f32 -> NHWC bf16 (float4 loads), fused avg-pool --------
__global__ void xcast_k(const float* __restrict__ x, unsigned short* __restrict__ xb,
                        float* __restrict__ pooled) {
  __shared__ unsigned short tile[64 * 260];  // 64 hw x 256 c (+4 pad)
  int b = blockIdx.y;
  int hw0 = blockIdx.x * 64;   // 49*64 = 3136
  int t = threadIdx.x;
  int p = t & 15, g = t >> 4;
#pragma unroll
  for (int i = 0; i < 16; ++i) {
    int c = g + 16 * i;
    float4 v = *(const float4*)(x + ((size_t)(b * 256 + c)) * 3136 + hw0 + p * 4);
    tile[(p * 4 + 0) * 260 + c] = f2bf(v.x);
    tile[(p * 4 + 1) * 260 + c] = f2bf(v.y);
    tile[(p * 4 + 2) * 260 + c] = f2bf(v.z);
    tile[(p * 4 + 3) * 260 + c] = f2bf(v.w);
  }
  __syncthreads();
  int lane = t & 63, wq = t >> 6;
  int c4 = lane * 4;
#pragma unroll
  for (int it = 0; it < 16; ++it) {
    int hl = it * 4 + wq;
    ushort4 v = *(const ushort4*)&tile[hl * 260 + c4];
    *(ushort4*)&xb[((size_t)(b * 3136 + hw0 + hl)) * 256 + c4] = v;
  }
  float s = 0.f;
#pragma unroll 16
  for (int hl = 0; hl < 64; ++hl) s += bf2f(tile[hl * 260 + t]);
  atomicAdd(&pooled[b * 256 + t], s * (1.0f / 3136.0f));
}

// ---------------- K2: attention (fc1->relu->fc2->softmax/T) + agg_b ----------------
__global__ void att_k(const float* __restrict__ pooled, const float* __restrict__ fc1,
                      const float* __restrict__ fc2w, const float* __restrict__ fc2b,
                      const float* __restrict__ bias, float* __restrict__ att,
                      float* __restrict__ aggb) {
  int b = blockIdx.x, t = threadIdx.x;   // 64 threads
  __shared__ float p[256];
  __shared__ float h[65];
  __shared__ float a4[4];
  for (int i = t; i < 256; i += 64) p[i] = pooled[b * 256 + i];
  __syncthreads();
  for (int j = t; j < 65; j += 64) {
    float s = 0.f;
    for (int c = 0; c < 256; ++c) s += p[c] * fc1[j * 256 + c];
    h[j] = fmaxf(s, 0.f);
  }
  __syncthreads();
  if (t == 0) {
    float lg[4];
    for (int k = 0; k < 4; ++k) {
      float s = fc2b[k];
      for (int j = 0; j < 65; ++j) s += h[j] * fc2w[k * 65 + j];
      lg[k] = s * (1.0f / 34.0f);
    }
    float m = fmaxf(fmaxf(lg[0], lg[1]), fmaxf(lg[2], lg[3]));
    float e0 = expf(lg[0] - m), e1 = expf(lg[1] - m), e2 = expf(lg[2] - m), e3 = expf(lg[3] - m);
    float inv = 1.0f / (e0 + e1 + e2 + e3);
    a4[0] = e0 * inv; a4[1] = e1 * inv; a4[2] = e2 * inv; a4[3] = e3 * inv;
    for (int k = 0; k < 4; ++k) att[b * 4 + k] = a4[k];
  }
  __syncthreads();
  for (int o = t; o < 256; o += 64) {
    float s = 0.f;
    for (int k = 0; k < 4; ++k) s += a4[k] * bias[k * 256 + o];
    aggb[b * 256 + o] = s;
  }
}

// ---------------- K3: agg_w -> [b][ot2][ic16][r9][ol128][il16] bf16 (plain) ----------
__global__ void aggw_k(const float* __restrict__ weight, const float* __restrict__ att,
                       unsigned short* __restrict__ aggw) {
  __shared__ float wl[4 * 2304];
  int o = blockIdx.x, t = threadIdx.x;   // t = input channel i
  for (int k = 0; k < 4; ++k)
    for (int idx = t; idx < 2304; idx += 256)
      wl[k * 2304 + idx] = weight[((size_t)(k * 256 + o)) * 2304 + idx];
  __syncthreads();
  int ot = o >> 7, ol = o & 127, ic = t >> 4, il = t & 15;
  int b0 = blockIdx.y * 8;
  for (int b = b0; b < b0 + 8; ++b) {
    float a0 = att[b * 4 + 0], a1 = att[b * 4 + 1], a2 = att[b * 4 + 2], a3 = att[b * 4 + 3];
    size_t base = ((size_t)((b * 2 + ot) * 16 + ic)) * (9 * 2048) + ol * 16 + il;
#pragma unroll
    for (int r = 0; r < 9; ++r) {
      float s = a0 * wl[t * 9 + r] + a1 * wl[2304 + t * 9 + r] +
                a2 * wl[4608 + t * 9 + r] + a3 * wl[6912 + t * 9 + r];
      aggw[base + r * 2048] = f2bf(s);
    }
  }
}

// ---------------- K4: conv; X 3-buf ring DMA + counted vmcnt; A 1-tap-ahead regs ----
// 256 thr (4 waves = 2wo x 2wn). Block tile 128o x 256n; wave 64o x 128n (2m x 4n).
// K: 16 chunks of 16 ch. LDS: X ring 3 x 16KB = 48KB static -> 2 blocks/CU.
// Schedule (T3/T4): DMA chunk ic+2 issued at top of compute(ic); end-of-chunk wait is
// s_waitcnt vmcnt(4) (drains chunk ic+1, issued a full chunk earlier) + raw s_barrier.
// A-loads are consumed (compiler-waited) before the counted wait -> count stays exact.
#define XBUF 16384

__global__ __launch_bounds__(256, 2) void conv_k(const unsigned short* __restrict__ xb,
                                                 const unsigned short* __restrict__ aggw,
                                                 const float* __restrict__ aggb,
                                                 const float* __restrict__ zerobuf,
                                                 float* __restrict__ out) {
  __shared__ __align__(16) unsigned char lds[3 * XBUF];
  const unsigned ldsbase = (unsigned)(size_t)&lds[0];
  const int t = threadIdx.x;
  const int wid = t >> 6, lane = t & 63, l31 = lane & 31, q = lane >> 5;
  const int wo = wid >> 1, wn = wid & 1;

  // XCD-chunked bijective swizzle: 832 blocks = 8 XCDs x 104; bn fastest within XCD
  int id = blockIdx.x;
  int wgid = (id & 7) * 104 + (id >> 3);
  int bn = wgid % 13;
  int rest = wgid / 13;          // = b*2 + bo
  int b = rest >> 1, bo = rest & 1;

  const int o0 = bo * 128;
  const int n0 = bn * 256;
  const int h0 = n0 / 56;

  // B (X-tile) fragment geometry (read side, forward swizzle)
  int bbase[4], nn[4], swz[4][3];
#pragma unroll
  for (int nf = 0; nf < 4; ++nf) {
    int n = n0 + wn * 128 + nf * 32 + l31;
    int h = n / 56, w = n - h * 56;
    nn[nf] = n;
    bbase[nf] = ((h - h0) * 64 + w) * 32 + q * 16;
#pragma unroll
    for (int dw = 0; dw < 3; ++dw) swz[nf][dw] = ((w + dw) & 7) << 4;
  }
  // A fragment global lane offsets (aggw layout == frag layout)
  int aoff[2];
#pragma unroll
  for (int mf = 0; mf < 2; ++mf) aoff[mf] = (wo * 64 + mf * 32 + l31) * 32 + q * 16;

  const char* xb_b = (const char*)xb + (size_t)b * 3136 * 512;
  const char* ag_c = (const char*)aggw + (size_t)rest * 589824;   // [16 ic][9 r][128 ol][16 il]*2B

  // X DMA source addresses (inverse swizzle -> linear LDS dest)
  const char* xg[4];
#pragma unroll
  for (int j = 0; j < 4; ++j) {
    int S = (j * 256 + t) * 16;
    int L = invswz(S);
    int pos = L >> 5, sub = (L >> 4) & 1;
    int row = pos >> 6, col = pos & 63;
    int hg = h0 - 1 + row, wg = col - 1;
    bool valid = (col >= 1 && col <= 56 && hg >= 0 && hg < 56);
    xg[j] = valid ? (xb_b + (size_t)(hg * 56 + wg) * 512 + sub * 16) : (const char*)zerobuf;
  }

  f32x16 acc[2][4];
#pragma unroll
  for (int i = 0; i < 2; ++i)
#pragma unroll
    for (int j = 0; j < 4; ++j)
#pragma unroll
      for (int e = 0; e < 16; ++e) acc[i][j][e] = 0.f;

  // prologue: DMA chunk0 -> buf0, chunk1 -> buf1; wait chunk0 (leave chunk1 in flight)
#pragma unroll
  for (int j = 0; j < 4; ++j) dma16(xg[j], ldsbase + j * 4096 + wid * 1024);
#pragma unroll
  for (int j = 0; j < 4; ++j) dma16(xg[j] + 32, ldsbase + XBUF + j * 4096 + wid * 1024);
  asm volatile("s_waitcnt vmcnt(4)" ::: "memory");
  __builtin_amdgcn_s_barrier();

  int cur = 0;
  for (int ic = 0; ic < 16; ++ic) {
    // DMA chunk ic+2 into ring slot (ic+2)%3. For ic>=14 source clamps to chunk 15
    // (junk-but-safe: target buffer already consumed, data never read).
    if (ic < 15) {
      int tgt = cur + 2; if (tgt >= 3) tgt -= 3;
      int icn = ic + 2 < 16 ? ic + 2 : 15;
#pragma unroll
      for (int j = 0; j < 4; ++j)
        dma16(xg[j] + icn * 32, ldsbase + tgt * XBUF + j * 4096 + wid * 1024);
      __builtin_amdgcn_sched_barrier(0);   // pin DMA issue ahead of compute stream
    }
    const char* agc = ag_c + (size_t)ic * 36864;
    const unsigned char* xlds = lds + cur * XBUF;
    // A tap-0 for this chunk
    bf16x8 a0c = *(const bf16x8*)(agc + aoff[0]);
    bf16x8 a1c = *(const bf16x8*)(agc + aoff[1]);
#pragma unroll
    for (int r = 0; r < 9; ++r) {
      const int dh = r / 3, dw = r % 3;
      // prefetch next tap's A while this tap's MFMAs run (~256 cyc cover)
      bf16x8 a0n, a1n;
      if (r < 8) {
        a0n = *(const bf16x8*)(agc + (r + 1) * 4096 + aoff[0]);
        a1n = *(const bf16x8*)(agc + (r + 1) * 4096 + aoff[1]);
      }
      bf16x8 b0 = *(const bf16x8*)(xlds + ((bbase[0] + dh * 2048 + dw * 32) ^ swz[0][dw]));
      bf16x8 b1 = *(const bf16x8*)(xlds + ((bbase[1] + dh * 2048 + dw * 32) ^ swz[1][dw]));
      bf16x8 b2 = *(const bf16x8*)(xlds + ((bbase[2] + dh * 2048 + dw * 32) ^ swz[2][dw]));
      bf16x8 b3 = *(const bf16x8*)(xlds + ((bbase[3] + dh * 2048 + dw * 32) ^ swz[3][dw]));
      __builtin_amdgcn_s_setprio(1);
      acc[0][0] = __builtin_amdgcn_mfma_f32_32x32x16_bf16(a0c, b0, acc[0][0], 0, 0, 0);
      acc[0][1] = __builtin_amdgcn_mfma_f32_32x32x16_bf16(a0c, b1, acc[0][1], 0, 0, 0);
      acc[0][2] = __builtin_amdgcn_mfma_f32_32x32x16_bf16(a0c, b2, acc[0][2], 0, 0, 0);
      acc[0][3] = __builtin_amdgcn_mfma_f32_32x32x16_bf16(a0c, b3, acc[0][3], 0, 0, 0);
      acc[1][0] = __builtin_amdgcn_mfma_f32_32x32x16_bf16(a1c, b0, acc[1][0], 0, 0, 0);
      acc[1][1] = __builtin_amdgcn_mfma_f32_32x32x16_bf16(a1c, b1, acc[1][1], 0, 0, 0);
      acc[1][2] = __builtin_amdgcn_mfma_f32_32x32x16_bf16(a1c, b2, acc[1][2], 0, 0, 0);
      acc[1][3] = __builtin_amdgcn_mfma_f32_32x32x16_bf16(a1c, b3, acc[1][3], 0, 0, 0);
      __builtin_amdgcn_s_setprio(0);
      if (r < 8) { a0c = a0n; a1c = a1n; }
    }
    if (ic < 15) {
      // counted wait (T4): outstanding = {ic+1: 4, ic+2: 4}; leave the newest 4 in flight
      asm volatile("s_waitcnt vmcnt(4)" ::: "memory");
      __builtin_amdgcn_s_barrier();
    }
    cur += 1; if (cur >= 3) cur -= 3;
  }
  asm volatile("s_waitcnt vmcnt(0)" ::: "memory");   // drain trailing junk DMAs

  // ---- epilogue: D layout col=lane&31 (n), row=(reg&3)+8*(reg>>2)+4*q (o)
#pragma unroll
  for (int mf = 0; mf < 2; ++mf) {
#pragma unroll
    for (int reg = 0; reg < 16; ++reg) {
      int o = o0 + wo * 64 + mf * 32 + (reg & 3) + 8 * (reg >> 2) + 4 * q;
      float ab = aggb[b * 256 + o];
      float* op = out + ((size_t)(b * 256 + o)) * 3136;
#pragma unroll
      for (int nf = 0; nf < 4; ++nf) {
        if (nn[nf] < 3136) op[nn[nf]] = acc[mf][nf][reg] + ab;
      }
    }
  }
}

extern "C" void kernel_launch(void* const* d_in, const int* in_sizes, int n_in,
                              void* d_out, int out_size, void* d_ws, size_t ws_size,
                              hipStream_t stream) {
  const float* x      = (const float*)d_in[0];
  const float* fc1    = (const float*)d_in[1];
  const float* fc2w   = (const float*)d_in[2];
  const float* fc2b   = (const float*)d_in[3];
  const float* weight = (const float*)d_in[4];
  const float* bias   = (const float*)d_in[5];
  float* out = (float*)d_out;

  char* ws = (char*)d_ws;
  float* pooled         = (float*)(ws);            // reused as zerobuf after att_k
  float* att            = (float*)(ws + 32768);
  float* aggb           = (float*)(ws + 33280);
  unsigned short* aggw  = (unsigned short*)(ws + 66048);
  unsigned short* xb    = (unsigned short*)(ws + 66048 + 37748736);

  hipMemsetAsync(pooled, 0, 32768, stream);          // pooled accumulated via atomics
  xcast_k<<<dim3(49, 32), 256, 0, stream>>>(x, xb, pooled);
  att_k<<<32, 64, 0, stream>>>(pooled, fc1, fc2w, fc2b, bias, att, aggb);
  hipMemsetAsync(pooled, 0, 1024, stream);           // pooled now dead -> 1KB zerobuf for halo
  aggw_k<<<dim3(256, 4), 256, 0, stream>>>(weight, att, aggw);
  conv_k<<<832, 256, 0, stream>>>(xb, aggw, aggb, (const float*)pooled, out);
}

// Round 10
// 226.126 us; speedup vs baseline: 1.2117x; 1.0502x over previous
//
#include <hip/hip_runtime.h>

// Shapes: x [32][256][56][56] f32; fc1_w [65][256]; fc2_w [4][65]; fc2_b [4];
//         weight [4][256][256][3][3] f32; bias [4][256]; out [32][256][56][56] f32
//
// ws layout (89,195,008 B):
//  [0)        pooled [32][256] f32 (REUSED as 1KB zerobuf for conv)   32768 B
//  [32768)    att    [32][4]  f32                                       512 B
//  [33280)    aggb   [32][256] f32                                    32768 B
//  [66048)    aggw   [32][2][16][9][128][16] bf16 (plain)        37,748,736 B
//  [37814784) xb     [32][3136][256] bf16 (NHWC, plain)          51,380,224 B

typedef short bf16x8 __attribute__((ext_vector_type(8)));
typedef float f32x16 __attribute__((ext_vector_type(16)));

__device__ __forceinline__ unsigned short f2bf(float f) {
  unsigned int u = __float_as_uint(f);
  return (unsigned short)((u + 0x7FFFu + ((u >> 16) & 1u)) >> 16);  // RNE
}
__device__ __forceinline__ float bf2f(unsigned short h) {
  return __uint_as_float(((unsigned int)h) << 16);
}

// forward LDS swizzle: S = L ^ (((L>>5)&7)<<4); inverse below (bit recurrence)
__device__ __forceinline__ int invswz(int S) {
  int b7 = (S >> 7) & 1;
  int b6 = ((S >> 6) & 1) ^ b7;
  int b5 = ((S >> 5) & 1) ^ b6;
  int b4 = ((S >> 4) & 1) ^ b5;
  return (S & ~0x70) | (b4 << 4) | (b5 << 5) | (b6 << 6);
}

typedef const __attribute__((address_space(1))) unsigned int* gas_t;
typedef __attribute__((address_space(3))) unsigned int* las_t;
__device__ __forceinline__ void dma16(const void* g, unsigned lds_addr) {
  __builtin_amdgcn_global_load_lds((gas_t)g, (las_t)(size_t)lds_addr, 16, 0, 0);
}

// ---------------- K1: x NCHW f32 -> NHWC bf16 (float4 loads), fused avg-pool --------
__global__ void xcast_k(const float* __restrict__ x, unsigned short* __restrict__ xb,
                        float* __restrict__ pooled) {
  __shared__ unsigned short tile[64 * 260];  // 64 hw x 256 c (+4 pad)
  int b = blockIdx.y;
  int hw0 = blockIdx.x * 64;   // 49*64 = 3136
  int t = threadIdx.x;
  int p = t & 15, g = t >> 4;
#pragma unroll
  for (int i = 0; i < 16; ++i) {
    int c = g + 16 * i;
    float4 v = *(const float4*)(x + ((size_t)(b * 256 + c)) * 3136 + hw0 + p * 4);
    tile[(p * 4 + 0) * 260 + c] = f2bf(v.x);
    tile[(p * 4 + 1) * 260 + c] = f2bf(v.y);
    tile[(p * 4 + 2) * 260 + c] = f2bf(v.z);
    tile[(p * 4 + 3) * 260 + c] = f2bf(v.w);
  }
  __syncthreads();
  int lane = t & 63, wq = t >> 6;
  int c4 = lane * 4;
#pragma unroll
  for (int it = 0; it < 16; ++it) {
    int hl = it * 4 + wq;
    ushort4 v = *(const ushort4*)&tile[hl * 260 + c4];
    *(ushort4*)&xb[((size_t)(b * 3136 + hw0 + hl)) * 256 + c4] = v;
  }
  float s = 0.f;
#pragma unroll 16
  for (int hl = 0; hl < 64; ++hl) s += bf2f(tile[hl * 260 + t]);
  atomicAdd(&pooled[b * 256 + t], s * (1.0f / 3136.0f));
}

// ---------------- K2: attention (fc1->relu->fc2->softmax/T) + agg_b ----------------
__global__ void att_k(const float* __restrict__ pooled, const float* __restrict__ fc1,
                      const float* __restrict__ fc2w, const float* __restrict__ fc2b,
                      const float* __restrict__ bias, float* __restrict__ att,
                      float* __restrict__ aggb) {
  int b = blockIdx.x, t = threadIdx.x;   // 64 threads
  __shared__ float p[256];
  __shared__ float h[65];
  __shared__ float a4[4];
  for (int i = t; i < 256; i += 64) p[i] = pooled[b * 256 + i];
  __syncthreads();
  for (int j = t; j < 65; j += 64) {
    float s = 0.f;
    for (int c = 0; c < 256; ++c) s += p[c] * fc1[j * 256 + c];
    h[j] = fmaxf(s, 0.f);
  }
  __syncthreads();
  if (t == 0) {
    float lg[4];
    for (int k = 0; k < 4; ++k) {
      float s = fc2b[k];
      for (int j = 0; j < 65; ++j) s += h[j] * fc2w[k * 65 + j];
      lg[k] = s * (1.0f / 34.0f);
    }
    float m = fmaxf(fmaxf(lg[0], lg[1]), fmaxf(lg[2], lg[3]));
    float e0 = expf(lg[0] - m), e1 = expf(lg[1] - m), e2 = expf(lg[2] - m), e3 = expf(lg[3] - m);
    float inv = 1.0f / (e0 + e1 + e2 + e3);
    a4[0] = e0 * inv; a4[1] = e1 * inv; a4[2] = e2 * inv; a4[3] = e3 * inv;
    for (int k = 0; k < 4; ++k) att[b * 4 + k] = a4[k];
  }
  __syncthreads();
  for (int o = t; o < 256; o += 64) {
    float s = 0.f;
    for (int k = 0; k < 4; ++k) s += a4[k] * bias[k * 256 + o];
    aggb[b * 256 + o] = s;
  }
}

// ---------------- K3: agg_w -> [b][ot2][ic16][r9][ol128][il16] bf16 (plain) ----------
__global__ void aggw_k(const float* __restrict__ weight, const float* __restrict__ att,
                       unsigned short* __restrict__ aggw) {
  __shared__ float wl[4 * 2304];
  int o = blockIdx.x, t = threadIdx.x;   // t = input channel i
  for (int k = 0; k < 4; ++k)
    for (int idx = t; idx < 2304; idx += 256)
      wl[k * 2304 + idx] = weight[((size_t)(k * 256 + o)) * 2304 + idx];
  __syncthreads();
  int ot = o >> 7, ol = o & 127, ic = t >> 4, il = t & 15;
  int b0 = blockIdx.y * 8;
  for (int b = b0; b < b0 + 8; ++b) {
    float a0 = att[b * 4 + 0], a1 = att[b * 4 + 1], a2 = att[b * 4 + 2], a3 = att[b * 4 + 3];
    size_t base = ((size_t)((b * 2 + ot) * 16 + ic)) * (9 * 2048) + ol * 16 + il;
#pragma unroll
    for (int r = 0; r < 9; ++r) {
      float s = a0 * wl[t * 9 + r] + a1 * wl[2304 + t * 9 + r] +
                a2 * wl[4608 + t * 9 + r] + a3 * wl[6912 + t * 9 + r];
      aggw[base + r * 2048] = f2bf(s);
    }
  }
}

// ---------------- K4: conv, occupancy-first: 64x64 wave tile, 12 waves/CU ----------
// 256 thr (4 waves = 2wo x 2wn). Block tile 128o x 128n; wave 64o x 64n (2m x 2n).
// acc = 64 AGPR/wave. K: 16 chunks of 16 ch. LDS: X dbuf 2 x 12KB (6 rows x 64 x 16ch).
// A: global->reg, 2-taps-ahead static pipeline. One barrier per chunk.
#define XBUF 12288

__global__ __launch_bounds__(256, 3) void conv_k(const unsigned short* __restrict__ xb,
                                                 const unsigned short* __restrict__ aggw,
                                                 const float* __restrict__ aggb,
                                                 const float* __restrict__ zerobuf,
                                                 float* __restrict__ out) {
  __shared__ __align__(16) unsigned char lds[2 * XBUF];
  const unsigned ldsbase = (unsigned)(size_t)&lds[0];
  const int t = threadIdx.x;
  const int wid = t >> 6, lane = t & 63, l31 = lane & 31, q = lane >> 5;
  const int wo = wid >> 1, wn = wid & 1;

  // XCD-chunked bijective swizzle: 1600 blocks = 8 XCDs x 200; bn fastest within XCD
  int id = blockIdx.x;
  int wgid = (id & 7) * 200 + (id >> 3);
  int bn = wgid % 25;
  int rest = wgid / 25;          // = b*2 + bo, in [0,64)
  int b = rest >> 1, bo = rest & 1;

  const int o0 = bo * 128;
  const int n0 = bn * 128;
  const int h0 = n0 / 56;

  // B (X-tile) fragment geometry (read side, forward swizzle); 2 n-frags per wave
  int bbase[2], nn[2], swz[2][3];
#pragma unroll
  for (int nf = 0; nf < 2; ++nf) {
    int n = n0 + wn * 64 + nf * 32 + l31;
    int h = n / 56, w = n - h * 56;
    nn[nf] = n;
    bbase[nf] = ((h - h0) * 64 + w) * 32 + q * 16;
#pragma unroll
    for (int dw = 0; dw < 3; ++dw) swz[nf][dw] = ((w + dw) & 7) << 4;
  }
  // A fragment global lane offsets (aggw layout == frag layout)
  int aoff[2];
#pragma unroll
  for (int mf = 0; mf < 2; ++mf) aoff[mf] = (wo * 64 + mf * 32 + l31) * 32 + q * 16;

  const char* xb_b = (const char*)xb + (size_t)b * 3136 * 512;
  const char* ag_c = (const char*)aggw + (size_t)rest * 589824;   // [16 ic][9 r][128 ol][16 il]*2B

  // X DMA source addresses (inverse swizzle -> linear LDS dest); 768 slots, 3/thread
  const char* xg[3];
#pragma unroll
  for (int j = 0; j < 3; ++j) {
    int S = (j * 256 + t) * 16;
    int L = invswz(S);
    int pos = L >> 5, sub = (L >> 4) & 1;
    int row = pos >> 6, col = pos & 63;       // 6 rows x 64 cols
    int hg = h0 - 1 + row, wg = col - 1;
    bool valid = (col >= 1 && col <= 56 && hg >= 0 && hg < 56);
    xg[j] = valid ? (xb_b + (size_t)(hg * 56 + wg) * 512 + sub * 16) : (const char*)zerobuf;
  }

  f32x16 acc[2][2];
#pragma unroll
  for (int i = 0; i < 2; ++i)
#pragma unroll
    for (int j = 0; j < 2; ++j)
#pragma unroll
      for (int e = 0; e < 16; ++e) acc[i][j][e] = 0.f;

  // prologue: DMA X chunk 0 -> buf 0
#pragma unroll
  for (int j = 0; j < 3; ++j) dma16(xg[j], ldsbase + j * 4096 + wid * 1024);
  __syncthreads();

  int cur = 0;
  for (int ic = 0; ic < 16; ++ic) {
    // X-DMA(ic+1) into other buffer; in flight across this chunk's MFMAs
    if (ic + 1 < 16) {
#pragma unroll
      for (int j = 0; j < 3; ++j)
        dma16(xg[j] + (ic + 1) * 32, ldsbase + (cur ^ 1) * XBUF + j * 4096 + wid * 1024);
      __builtin_amdgcn_sched_barrier(0);   // pin DMA issue ahead of compute stream
    }
    const char* agc = ag_c + (size_t)ic * 36864;
    const unsigned char* xlds = lds + cur * XBUF;
    // A pipeline: 2 taps ahead (static r&1 indexing, fully unrolled loop)
    bf16x8 a0s[2], a1s[2];
    a0s[0] = *(const bf16x8*)(agc + aoff[0]);
    a1s[0] = *(const bf16x8*)(agc + aoff[1]);
    a0s[1] = *(const bf16x8*)(agc + 4096 + aoff[0]);
    a1s[1] = *(const bf16x8*)(agc + 4096 + aoff[1]);
#pragma unroll
    for (int r = 0; r < 9; ++r) {
      const int dh = r / 3, dw = r % 3;
      bf16x8 c0 = a0s[r & 1], c1 = a1s[r & 1];
      if (r + 2 < 9) {
        a0s[r & 1] = *(const bf16x8*)(agc + (r + 2) * 4096 + aoff[0]);
        a1s[r & 1] = *(const bf16x8*)(agc + (r + 2) * 4096 + aoff[1]);
      }
      bf16x8 b0 = *(const bf16x8*)(xlds + ((bbase[0] + dh * 2048 + dw * 32) ^ swz[0][dw]));
      bf16x8 b1 = *(const bf16x8*)(xlds + ((bbase[1] + dh * 2048 + dw * 32) ^ swz[1][dw]));
      __builtin_amdgcn_s_setprio(1);
      acc[0][0] = __builtin_amdgcn_mfma_f32_32x32x16_bf16(c0, b0, acc[0][0], 0, 0, 0);
      acc[0][1] = __builtin_amdgcn_mfma_f32_32x32x16_bf16(c0, b1, acc[0][1], 0, 0, 0);
      acc[1][0] = __builtin_amdgcn_mfma_f32_32x32x16_bf16(c1, b0, acc[1][0], 0, 0, 0);
      acc[1][1] = __builtin_amdgcn_mfma_f32_32x32x16_bf16(c1, b1, acc[1][1], 0, 0, 0);
      __builtin_amdgcn_s_setprio(0);
    }
    __syncthreads();   // X(ic+1) DMA drained (issued ~1150 cyc earlier); buffers swap
    cur ^= 1;
  }

  // ---- epilogue: D layout col=lane&31 (n), row=(reg&3)+8*(reg>>2)+4*q (o)
#pragma unroll
  for (int mf = 0; mf < 2; ++mf) {
#pragma unroll
    for (int reg = 0; reg < 16; ++reg) {
      int o = o0 + wo * 64 + mf * 32 + (reg & 3) + 8 * (reg >> 2) + 4 * q;
      float ab = aggb[b * 256 + o];
      float* op = out + ((size_t)(b * 256 + o)) * 3136;
#pragma unroll
      for (int nf = 0; nf < 2; ++nf) {
        if (nn[nf] < 3136) op[nn[nf]] = acc[mf][nf][reg] + ab;
      }
    }
  }
}

extern "C" void kernel_launch(void* const* d_in, const int* in_sizes, int n_in,
                              void* d_out, int out_size, void* d_ws, size_t ws_size,
                              hipStream_t stream) {
  const float* x      = (const float*)d_in[0];
  const float* fc1    = (const float*)d_in[1];
  const float* fc2w   = (const float*)d_in[2];
  const float* fc2b   = (const float*)d_in[3];
  const float* weight = (const float*)d_in[4];
  const float* bias   = (const float*)d_in[5];
  float* out = (float*)d_out;

  char* ws = (char*)d_ws;
  float* pooled         = (float*)(ws);            // reused as zerobuf after att_k
  float* att            = (float*)(ws + 32768);
  float* aggb           = (float*)(ws + 33280);
  unsigned short* aggw  = (unsigned short*)(ws + 66048);
  unsigned short* xb    = (unsigned short*)(ws + 66048 + 37748736);

  hipMemsetAsync(pooled, 0, 32768, stream);          // pooled accumulated via atomics
  xcast_k<<<dim3(49, 32), 256, 0, stream>>>(x, xb, pooled);
  att_k<<<32, 64, 0, stream>>>(pooled, fc1, fc2w, fc2b, bias, att, aggb);
  hipMemsetAsync(pooled, 0, 1024, stream);           // pooled now dead -> 1KB zerobuf for halo
  aggw_k<<<dim3(256, 4), 256, 0, stream>>>(weight, att, aggw);
  conv_k<<<1600, 256, 0, stream>>>(xb, aggw, aggb, (const float*)pooled, out);
}

// Round 11
// 225.430 us; speedup vs baseline: 1.2155x; 1.0031x over previous
//
#include <hip/hip_runtime.h>

// Shapes: x [32][256][56][56] f32; fc1_w [65][256]; fc2_w [4][65]; fc2_b [4];
//         weight [4][256][256][3][3] f32; bias [4][256]; out [32][256][56][56] f32
//
// ws layout (89,195,008 B):
//  [0)        pooled [32][256] f32 (REUSED as 1KB zerobuf for conv)   32768 B
//  [32768)    att    [32][4]  f32                                       512 B
//  [33280)    aggb   [32][256] f32                                    32768 B
//  [66048)    aggw   [32][2][16][9][128][16] bf16 (plain)        37,748,736 B
//  [37814784) xb     [32][3136][256] bf16 (NHWC, plain)          51,380,224 B

typedef short bf16x8 __attribute__((ext_vector_type(8)));
typedef float f32x16 __attribute__((ext_vector_type(16)));

__device__ __forceinline__ unsigned short f2bf(float f) {
  unsigned int u = __float_as_uint(f);
  return (unsigned short)((u + 0x7FFFu + ((u >> 16) & 1u)) >> 16);  // RNE
}
__device__ __forceinline__ float bf2f(unsigned short h) {
  return __uint_as_float(((unsigned int)h) << 16);
}

// forward LDS swizzle: S = L ^ (((L>>5)&7)<<4); inverse below (bit recurrence)
__device__ __forceinline__ int invswz(int S) {
  int b7 = (S >> 7) & 1;
  int b6 = ((S >> 6) & 1) ^ b7;
  int b5 = ((S >> 5) & 1) ^ b6;
  int b4 = ((S >> 4) & 1) ^ b5;
  return (S & ~0x70) | (b4 << 4) | (b5 << 5) | (b6 << 6);
}

typedef const __attribute__((address_space(1))) unsigned int* gas_t;
typedef __attribute__((address_space(3))) unsigned int* las_t;
__device__ __forceinline__ void dma16(const void* g, unsigned lds_addr) {
  __builtin_amdgcn_global_load_lds((gas_t)g, (las_t)(size_t)lds_addr, 16, 0, 0);
}

// ---------------- K1: x NCHW f32 -> NHWC bf16 (float4 loads), fused avg-pool --------
__global__ void xcast_k(const float* __restrict__ x, unsigned short* __restrict__ xb,
                        float* __restrict__ pooled) {
  __shared__ unsigned short tile[64 * 260];  // 64 hw x 256 c (+4 pad)
  int b = blockIdx.y;
  int hw0 = blockIdx.x * 64;   // 49*64 = 3136
  int t = threadIdx.x;
  int p = t & 15, g = t >> 4;
#pragma unroll
  for (int i = 0; i < 16; ++i) {
    int c = g + 16 * i;
    float4 v = *(const float4*)(x + ((size_t)(b * 256 + c)) * 3136 + hw0 + p * 4);
    tile[(p * 4 + 0) * 260 + c] = f2bf(v.x);
    tile[(p * 4 + 1) * 260 + c] = f2bf(v.y);
    tile[(p * 4 + 2) * 260 + c] = f2bf(v.z);
    tile[(p * 4 + 3) * 260 + c] = f2bf(v.w);
  }
  __syncthreads();
  int lane = t & 63, wq = t >> 6;
  int c4 = lane * 4;
#pragma unroll
  for (int it = 0; it < 16; ++it) {
    int hl = it * 4 + wq;
    ushort4 v = *(const ushort4*)&tile[hl * 260 + c4];
    *(ushort4*)&xb[((size_t)(b * 3136 + hw0 + hl)) * 256 + c4] = v;
  }
  float s = 0.f;
#pragma unroll 16
  for (int hl = 0; hl < 64; ++hl) s += bf2f(tile[hl * 260 + t]);
  atomicAdd(&pooled[b * 256 + t], s * (1.0f / 3136.0f));
}

// ---------------- K2: attention (fc1->relu->fc2->softmax/T) + agg_b ----------------
__global__ void att_k(const float* __restrict__ pooled, const float* __restrict__ fc1,
                      const float* __restrict__ fc2w, const float* __restrict__ fc2b,
                      const float* __restrict__ bias, float* __restrict__ att,
                      float* __restrict__ aggb) {
  int b = blockIdx.x, t = threadIdx.x;   // 64 threads
  __shared__ float p[256];
  __shared__ float h[65];
  __shared__ float a4[4];
  for (int i = t; i < 256; i += 64) p[i] = pooled[b * 256 + i];
  __syncthreads();
  for (int j = t; j < 65; j += 64) {
    float s = 0.f;
    for (int c = 0; c < 256; ++c) s += p[c] * fc1[j * 256 + c];
    h[j] = fmaxf(s, 0.f);
  }
  __syncthreads();
  if (t == 0) {
    float lg[4];
    for (int k = 0; k < 4; ++k) {
      float s = fc2b[k];
      for (int j = 0; j < 65; ++j) s += h[j] * fc2w[k * 65 + j];
      lg[k] = s * (1.0f / 34.0f);
    }
    float m = fmaxf(fmaxf(lg[0], lg[1]), fmaxf(lg[2], lg[3]));
    float e0 = expf(lg[0] - m), e1 = expf(lg[1] - m), e2 = expf(lg[2] - m), e3 = expf(lg[3] - m);
    float inv = 1.0f / (e0 + e1 + e2 + e3);
    a4[0] = e0 * inv; a4[1] = e1 * inv; a4[2] = e2 * inv; a4[3] = e3 * inv;
    for (int k = 0; k < 4; ++k) att[b * 4 + k] = a4[k];
  }
  __syncthreads();
  for (int o = t; o < 256; o += 64) {
    float s = 0.f;
    for (int k = 0; k < 4; ++k) s += a4[k] * bias[k * 256 + o];
    aggb[b * 256 + o] = s;
  }
}

// ---------------- K3: agg_w -> [b][ot2][ic16][r9][ol128][il16] bf16 (plain) ----------
__global__ void aggw_k(const float* __restrict__ weight, const float* __restrict__ att,
                       unsigned short* __restrict__ aggw) {
  __shared__ float wl[4 * 2304];
  int o = blockIdx.x, t = threadIdx.x;   // t = input channel i
  for (int k = 0; k < 4; ++k)
    for (int idx = t; idx < 2304; idx += 256)
      wl[k * 2304 + idx] = weight[((size_t)(k * 256 + o)) * 2304 + idx];
  __syncthreads();
  int ot = o >> 7, ol = o & 127, ic = t >> 4, il = t & 15;
  int b0 = blockIdx.y * 8;
  for (int b = b0; b < b0 + 8; ++b) {
    float a0 = att[b * 4 + 0], a1 = att[b * 4 + 1], a2 = att[b * 4 + 2], a3 = att[b * 4 + 3];
    size_t base = ((size_t)((b * 2 + ot) * 16 + ic)) * (9 * 2048) + ol * 16 + il;
#pragma unroll
    for (int r = 0; r < 9; ++r) {
      float s = a0 * wl[t * 9 + r] + a1 * wl[2304 + t * 9 + r] +
                a2 * wl[4608 + t * 9 + r] + a3 * wl[6912 + t * 9 + r];
      aggw[base + r * 2048] = f2bf(s);
    }
  }
}

// ---------------- K4: conv, issue-order-correct pipeline ----------------------------
// 256 thr (4 waves = 2wo x 2wn). Block tile 128o x 128n; wave 64o x 64n (2m x 2n).
// K: 16 chunks of 16 ch. LDS: X dbuf 2 x 12KB. A: global->reg 2-taps-ahead;
// B: LDS->reg 1-tap-ahead (MFMA never waits on a just-issued ds_read).
// X-DMA for chunk ic+1 issued at tap 6, AFTER the last A-load of chunk ic ->
// no A-wait (vmcnt is FIFO) ever implies a fresh-DMA wait; barrier sees ~384-cyc-old DMAs.
#define XBUF 12288

__global__ __launch_bounds__(256, 3) void conv_k(const unsigned short* __restrict__ xb,
                                                 const unsigned short* __restrict__ aggw,
                                                 const float* __restrict__ aggb,
                                                 const float* __restrict__ zerobuf,
                                                 float* __restrict__ out) {
  __shared__ __align__(16) unsigned char lds[2 * XBUF];
  const unsigned ldsbase = (unsigned)(size_t)&lds[0];
  const int t = threadIdx.x;
  const int wid = t >> 6, lane = t & 63, l31 = lane & 31, q = lane >> 5;
  const int wo = wid >> 1, wn = wid & 1;

  // XCD-chunked bijective swizzle: 1600 blocks = 8 XCDs x 200; bn fastest within XCD
  int id = blockIdx.x;
  int wgid = (id & 7) * 200 + (id >> 3);
  int bn = wgid % 25;
  int rest = wgid / 25;          // = b*2 + bo, in [0,64)
  int b = rest >> 1, bo = rest & 1;

  const int o0 = bo * 128;
  const int n0 = bn * 128;
  const int h0 = n0 / 56;

  // B (X-tile) fragment geometry (read side, forward swizzle); 2 n-frags per wave
  int bbase[2], nn[2], swz[2][3];
#pragma unroll
  for (int nf = 0; nf < 2; ++nf) {
    int n = n0 + wn * 64 + nf * 32 + l31;
    int h = n / 56, w = n - h * 56;
    nn[nf] = n;
    bbase[nf] = ((h - h0) * 64 + w) * 32 + q * 16;
#pragma unroll
    for (int dw = 0; dw < 3; ++dw) swz[nf][dw] = ((w + dw) & 7) << 4;
  }
  // A fragment global lane offsets (aggw layout == frag layout)
  int aoff[2];
#pragma unroll
  for (int mf = 0; mf < 2; ++mf) aoff[mf] = (wo * 64 + mf * 32 + l31) * 32 + q * 16;

  const char* xb_b = (const char*)xb + (size_t)b * 3136 * 512;
  const char* ag_c = (const char*)aggw + (size_t)rest * 589824;   // [16 ic][9 r][128 ol][16 il]*2B

  // X DMA source addresses (inverse swizzle -> linear LDS dest); 768 slots, 3/thread
  const char* xg[3];
#pragma unroll
  for (int j = 0; j < 3; ++j) {
    int S = (j * 256 + t) * 16;
    int L = invswz(S);
    int pos = L >> 5, sub = (L >> 4) & 1;
    int row = pos >> 6, col = pos & 63;       // 6 rows x 64 cols
    int hg = h0 - 1 + row, wg = col - 1;
    bool valid = (col >= 1 && col <= 56 && hg >= 0 && hg < 56);
    xg[j] = valid ? (xb_b + (size_t)(hg * 56 + wg) * 512 + sub * 16) : (const char*)zerobuf;
  }

  f32x16 acc[2][2];
#pragma unroll
  for (int i = 0; i < 2; ++i)
#pragma unroll
    for (int j = 0; j < 2; ++j)
#pragma unroll
      for (int e = 0; e < 16; ++e) acc[i][j][e] = 0.f;

  // prologue: DMA X chunk 0 -> buf 0
#pragma unroll
  for (int j = 0; j < 3; ++j) dma16(xg[j], ldsbase + j * 4096 + wid * 1024);
  __syncthreads();

  int cur = 0;
  for (int ic = 0; ic < 16; ++ic) {
    const char* agc = ag_c + (size_t)ic * 36864;
    const unsigned char* xlds = lds + cur * XBUF;
    // A pipeline (2 taps ahead) and B pipeline (1 tap ahead) primed
    bf16x8 a0s0 = *(const bf16x8*)(agc + aoff[0]);
    bf16x8 a1s0 = *(const bf16x8*)(agc + aoff[1]);
    bf16x8 a0s1 = *(const bf16x8*)(agc + 4096 + aoff[0]);
    bf16x8 a1s1 = *(const bf16x8*)(agc + 4096 + aoff[1]);
    bf16x8 b0c = *(const bf16x8*)(xlds + (bbase[0] ^ swz[0][0]));
    bf16x8 b1c = *(const bf16x8*)(xlds + (bbase[1] ^ swz[1][0]));
#pragma unroll
    for (int r = 0; r < 9; ++r) {
      // B(r+1) from LDS, issued before MFMA(r)
      bf16x8 b0n, b1n;
      if (r + 1 < 9) {
        const int dh = (r + 1) / 3, dw = (r + 1) % 3;
        b0n = *(const bf16x8*)(xlds + ((bbase[0] + dh * 2048 + dw * 32) ^ swz[0][dw]));
        b1n = *(const bf16x8*)(xlds + ((bbase[1] + dh * 2048 + dw * 32) ^ swz[1][dw]));
      }
      // A(r+2) from global (static 2-slot rotation)
      bf16x8 c0, c1;
      if ((r & 1) == 0) { c0 = a0s0; c1 = a1s0; } else { c0 = a0s1; c1 = a1s1; }
      if (r + 2 < 9) {
        if ((r & 1) == 0) {
          a0s0 = *(const bf16x8*)(agc + (r + 2) * 4096 + aoff[0]);
          a1s0 = *(const bf16x8*)(agc + (r + 2) * 4096 + aoff[1]);
        } else {
          a0s1 = *(const bf16x8*)(agc + (r + 2) * 4096 + aoff[0]);
          a1s1 = *(const bf16x8*)(agc + (r + 2) * 4096 + aoff[1]);
        }
      }
      // X-DMA(ic+1) at tap 6: after the chunk's last A-load (issued r=6? no - r=6 issues
      // A(8), the final one, just above) -> all A-waits precede DMAs in vmcnt order.
      if (r == 6 && ic + 1 < 16) {
#pragma unroll
        for (int j = 0; j < 3; ++j)
          dma16(xg[j] + (ic + 1) * 32, ldsbase + (cur ^ 1) * XBUF + j * 4096 + wid * 1024);
        __builtin_amdgcn_sched_barrier(0);   // pin: DMAs stay after A-loads, before tail MFMAs
      }
      __builtin_amdgcn_s_setprio(1);
      acc[0][0] = __builtin_amdgcn_mfma_f32_32x32x16_bf16(c0, b0c, acc[0][0], 0, 0, 0);
      acc[0][1] = __builtin_amdgcn_mfma_f32_32x32x16_bf16(c0, b1c, acc[0][1], 0, 0, 0);
      acc[1][0] = __builtin_amdgcn_mfma_f32_32x32x16_bf16(c1, b0c, acc[1][0], 0, 0, 0);
      acc[1][1] = __builtin_amdgcn_mfma_f32_32x32x16_bf16(c1, b1c, acc[1][1], 0, 0, 0);
      __builtin_amdgcn_s_setprio(0);
      if (r + 1 < 9) { b0c = b0n; b1c = b1n; }
    }
    __syncthreads();   // X(ic+1) DMA drained (issued 3 taps = ~400 cyc earlier)
    cur ^= 1;
  }

  // ---- epilogue: D layout col=lane&31 (n), row=(reg&3)+8*(reg>>2)+4*q (o)
#pragma unroll
  for (int mf = 0; mf < 2; ++mf) {
#pragma unroll
    for (int reg = 0; reg < 16; ++reg) {
      int o = o0 + wo * 64 + mf * 32 + (reg & 3) + 8 * (reg >> 2) + 4 * q;
      float ab = aggb[b * 256 + o];
      float* op = out + ((size_t)(b * 256 + o)) * 3136;
#pragma unroll
      for (int nf = 0; nf < 2; ++nf) {
        if (nn[nf] < 3136) op[nn[nf]] = acc[mf][nf][reg] + ab;
      }
    }
  }
}

extern "C" void kernel_launch(void* const* d_in, const int* in_sizes, int n_in,
                              void* d_out, int out_size, void* d_ws, size_t ws_size,
                              hipStream_t stream) {
  const float* x      = (const float*)d_in[0];
  const float* fc1    = (const float*)d_in[1];
  const float* fc2w   = (const float*)d_in[2];
  const float* fc2b   = (const float*)d_in[3];
  const float* weight = (const float*)d_in[4];
  const float* bias   = (const float*)d_in[5];
  float* out = (float*)d_out;

  char* ws = (char*)d_ws;
  float* pooled         = (float*)(ws);            // reused as zerobuf after att_k
  float* att            = (float*)(ws + 32768);
  float* aggb           = (float*)(ws + 33280);
  unsigned short* aggw  = (unsigned short*)(ws + 66048);
  unsigned short* xb    = (unsigned short*)(ws + 66048 + 37748736);

  hipMemsetAsync(pooled, 0, 32768, stream);          // pooled accumulated via atomics
  xcast_k<<<dim3(49, 32), 256, 0, stream>>>(x, xb, pooled);
  att_k<<<32, 64, 0, stream>>>(pooled, fc1, fc2w, fc2b, bias, att, aggb);
  hipMemsetAsync(pooled, 0, 1024, stream);           // pooled now dead -> 1KB zerobuf for halo
  aggw_k<<<dim3(256, 4), 256, 0, stream>>>(weight, att, aggw);
  conv_k<<<1600, 256, 0, stream>>>(xb, aggw, aggb, (const float*)pooled, out);
}